// Round 1
// baseline (272.234 us; speedup 1.0000x reference)
//
#include <hip/hip_runtime.h>
#include <math.h>

#define NB   4
#define HH   64
#define WW   64
#define CCH  256
#define GG   8
#define CGC  32
#define HI   66
#define NPIX 16384
#define OMW  216   // 144 offsets + 72 mask logits

// ---------------- generic fp32 tiled GEMM ----------------
// C[M,Nn] = A[M,Kk] @ B[Kk,Nn] + bias
// MODE 0: out[row*Nn + col]
// MODE 1: out is xpad [N,66,66,256]; row is pixel index, stored at (h+1,w+1)
template<int MODE>
__global__ __launch_bounds__(256)
void gemm_f32(const float* __restrict__ A, const float* __restrict__ B,
              const float* __restrict__ bias, float* __restrict__ out,
              int M, int Nn, int Kk)
{
    __shared__ float As[16][64];
    __shared__ float Bs[16][64];
    const int tid = threadIdx.x;
    const int tm = tid >> 4, tn = tid & 15;
    const int row0 = blockIdx.x * 64, col0 = blockIdx.y * 64;

    const int lam = tid >> 2;          // 0..63  (A row within tile)
    const int lak = (tid & 3) << 2;    // 0,4,8,12 (A k within tile)
    const int lbk = tid >> 4;          // 0..15  (B k within tile)
    const int lbn = (tid & 15) << 2;   // 0..60  (B col within tile)

    float acc[4][4] = {};

    for (int kb = 0; kb < Kk; kb += 16) {
        float4 av = *reinterpret_cast<const float4*>(A + (size_t)(row0 + lam) * Kk + kb + lak);
        As[lak + 0][lam] = av.x;
        As[lak + 1][lam] = av.y;
        As[lak + 2][lam] = av.z;
        As[lak + 3][lam] = av.w;

        int bcol = col0 + lbn;
        float4 bv;
        const float* brow = B + (size_t)(kb + lbk) * Nn;
        if (bcol + 3 < Nn) {
            bv = *reinterpret_cast<const float4*>(brow + bcol);
        } else {
            bv.x = (bcol + 0 < Nn) ? brow[bcol + 0] : 0.f;
            bv.y = (bcol + 1 < Nn) ? brow[bcol + 1] : 0.f;
            bv.z = (bcol + 2 < Nn) ? brow[bcol + 2] : 0.f;
            bv.w = (bcol + 3 < Nn) ? brow[bcol + 3] : 0.f;
        }
        Bs[lbk][lbn + 0] = bv.x;
        Bs[lbk][lbn + 1] = bv.y;
        Bs[lbk][lbn + 2] = bv.z;
        Bs[lbk][lbn + 3] = bv.w;

        __syncthreads();
        #pragma unroll
        for (int k = 0; k < 16; ++k) {
            float a0 = As[k][tm * 4 + 0];
            float a1 = As[k][tm * 4 + 1];
            float a2 = As[k][tm * 4 + 2];
            float a3 = As[k][tm * 4 + 3];
            float b0 = Bs[k][tn * 4 + 0];
            float b1 = Bs[k][tn * 4 + 1];
            float b2 = Bs[k][tn * 4 + 2];
            float b3 = Bs[k][tn * 4 + 3];
            acc[0][0] += a0 * b0; acc[0][1] += a0 * b1; acc[0][2] += a0 * b2; acc[0][3] += a0 * b3;
            acc[1][0] += a1 * b0; acc[1][1] += a1 * b1; acc[1][2] += a1 * b2; acc[1][3] += a1 * b3;
            acc[2][0] += a2 * b0; acc[2][1] += a2 * b1; acc[2][2] += a2 * b2; acc[2][3] += a2 * b3;
            acc[3][0] += a3 * b0; acc[3][1] += a3 * b1; acc[3][2] += a3 * b2; acc[3][3] += a3 * b3;
        }
        __syncthreads();
    }

    #pragma unroll
    for (int i = 0; i < 4; ++i) {
        int row = row0 + tm * 4 + i;
        float* dst;
        if (MODE == 1) {
            int n = row >> 12;
            int hw = row & 4095;
            int h = hw >> 6, w = hw & 63;
            dst = out + (size_t)((n * HI + h + 1) * HI + (w + 1)) * CCH;
        } else {
            dst = out + (size_t)row * Nn;
        }
        #pragma unroll
        for (int j = 0; j < 4; ++j) {
            int col = col0 + tn * 4 + j;
            if (col < Nn) dst[col] = acc[i][j] + bias[col];
        }
    }
}

// ---------------- pack off_w|mask_w into one [256,216] matrix ----------------
__global__ __launch_bounds__(256)
void pack_offmask(const float* __restrict__ off_w, const float* __restrict__ off_b,
                  const float* __restrict__ mask_w, const float* __restrict__ mask_b,
                  float* __restrict__ W2, float* __restrict__ b2)
{
    int t = blockIdx.x * 256 + threadIdx.x;
    if (t < 256 * OMW) {
        int k = t / OMW, j = t % OMW;
        W2[t] = (j < 144) ? off_w[k * 144 + j] : mask_w[k * 72 + (j - 144)];
    }
    if (t < OMW) b2[t] = (t < 144) ? off_b[t] : mask_b[t - 144];
}

// ---------------- depthwise 3x3 + BN(inference) + SiLU ----------------
__global__ __launch_bounds__(256)
void dw_bn_silu(const float* __restrict__ x, const float* __restrict__ dwk,
                const float* __restrict__ bg, const float* __restrict__ bb,
                const float* __restrict__ bmv, const float* __restrict__ bvv,
                float* __restrict__ x1)
{
    int pix = blockIdx.x;
    int n = pix >> 12, hw = pix & 4095, h = hw >> 6, w = hw & 63;
    int c = threadIdx.x;
    float acc = 0.f;
    #pragma unroll
    for (int kh = 0; kh < 3; ++kh) {
        int hh = h + kh - 1;
        if (hh < 0 || hh >= HH) continue;
        #pragma unroll
        for (int kw = 0; kw < 3; ++kw) {
            int ww = w + kw - 1;
            if (ww < 0 || ww >= WW) continue;
            acc += x[(size_t)((n * HH + hh) * WW + ww) * CCH + c] * dwk[c * 9 + kh * 3 + kw];
        }
    }
    float y = bg[c] * (acc - bmv[c]) * rsqrtf(bvv[c] + 1e-5f) + bb[c];
    y = y / (1.f + expf(-y));
    x1[(size_t)pix * CCH + c] = y;
}

// ---------------- DCNv3 core: softmax + bilinear sampling ----------------
__global__ __launch_bounds__(256)
void dcn_sample(const float* __restrict__ xpad, const float* __restrict__ om,
                float* __restrict__ core)
{
    int pix = blockIdx.x;
    int n = pix >> 12, hw = pix & 4095, h = hw >> 6, w = hw & 63;
    int t = threadIdx.x;
    int g = t >> 5, cg = t & 31;
    const float* omp = om + (size_t)pix * OMW;

    // per-group softmax over 9 points (redundant across the 32 lanes of the group)
    float lg[9], mx = -1e30f;
    #pragma unroll
    for (int p = 0; p < 9; ++p) { lg[p] = omp[144 + g * 9 + p]; mx = fmaxf(mx, lg[p]); }
    float s = 0.f;
    #pragma unroll
    for (int p = 0; p < 9; ++p) { lg[p] = expf(lg[p] - mx); s += lg[p]; }
    float inv = 1.f / s;

    const float* img = xpad + (size_t)n * HI * HI * CCH + g * CGC + cg;
    float acc = 0.f;
    #pragma unroll
    for (int p = 0; p < 9; ++p) {
        float ox = omp[g * 18 + p * 2 + 0];
        float oy = omp[g * 18 + p * 2 + 1];
        // padded-image coords: center (w+1,h+1) + kernel offset + learned offset
        float xi = (float)(w + (p / 3)) + ox;   // w + 1 + (p/3 - 1)
        float yi = (float)(h + (p % 3)) + oy;
        float x0f = floorf(xi), y0f = floorf(yi);
        int x0 = (int)x0f, y0 = (int)y0f;
        float fx = xi - x0f, fy = yi - y0f;
        float wgt = lg[p] * inv;
        float w00 = (1.f - fx) * (1.f - fy) * wgt;
        float w10 = fx * (1.f - fy) * wgt;
        float w01 = (1.f - fx) * fy * wgt;
        float w11 = fx * fy * wgt;
        if ((unsigned)x0 < HI && (unsigned)y0 < HI)
            acc += w00 * img[(size_t)(y0 * HI + x0) * CCH];
        if ((unsigned)(x0 + 1) < HI && (unsigned)y0 < HI)
            acc += w10 * img[(size_t)(y0 * HI + x0 + 1) * CCH];
        if ((unsigned)x0 < HI && (unsigned)(y0 + 1) < HI)
            acc += w01 * img[(size_t)((y0 + 1) * HI + x0) * CCH];
        if ((unsigned)(x0 + 1) < HI && (unsigned)(y0 + 1) < HI)
            acc += w11 * img[(size_t)((y0 + 1) * HI + x0 + 1) * CCH];
    }
    core[(size_t)pix * CCH + g * CGC + cg] = acc;
}

extern "C" void kernel_launch(void* const* d_in, const int* in_sizes, int n_in,
                              void* d_out, int out_size, void* d_ws, size_t ws_size,
                              hipStream_t stream) {
    const float* x      = (const float*)d_in[0];
    const float* in_w   = (const float*)d_in[1];
    const float* in_b   = (const float*)d_in[2];
    const float* out_w  = (const float*)d_in[3];
    const float* out_b  = (const float*)d_in[4];
    const float* off_w  = (const float*)d_in[5];
    const float* off_b  = (const float*)d_in[6];
    const float* mask_w = (const float*)d_in[7];
    const float* mask_b = (const float*)d_in[8];
    const float* dw_k   = (const float*)d_in[9];
    const float* bn_g   = (const float*)d_in[10];
    const float* bn_b   = (const float*)d_in[11];
    const float* bn_m   = (const float*)d_in[12];
    const float* bn_v   = (const float*)d_in[13];

    float* ws   = (float*)d_ws;
    float* xpad = ws;                       // 4*66*66*256 = 4,460,544 floats
    float* x1   = xpad + 4460544;           // 16384*256 = 4,194,304 (reused as 'core')
    float* offm = x1 + 4194304;             // 16384*216 = 3,538,944
    float* W2   = offm + 3538944;           // 256*216 = 55,296
    float* b2   = W2 + 55296;               // 216
    float* core = x1;                       // alias: x1 dead after offm GEMM

    // zero the padded image (border ring must be 0 every call)
    hipMemsetAsync(xpad, 0, (size_t)4460544 * sizeof(float), stream);

    pack_offmask<<<(256 * OMW + 255) / 256, 256, 0, stream>>>(off_w, off_b, mask_w, mask_b, W2, b2);

    // 1) input projection -> padded image interior
    gemm_f32<1><<<dim3(NPIX / 64, 4), 256, 0, stream>>>(x, in_w, in_b, xpad, NPIX, 256, 256);

    // 2) depthwise conv + BN + SiLU
    dw_bn_silu<<<NPIX, 256, 0, stream>>>(x, dw_k, bn_g, bn_b, bn_m, bn_v, x1);

    // 3) offset + mask projection (fused GEMM, N=216)
    gemm_f32<0><<<dim3(NPIX / 64, (OMW + 63) / 64), 256, 0, stream>>>(x1, W2, b2, offm, NPIX, OMW, 256);

    // 4) deformable sampling (softmax in-register)
    dcn_sample<<<NPIX, 256, 0, stream>>>(xpad, offm, core);

    // 5) output projection -> d_out
    gemm_f32<0><<<dim3(NPIX / 64, 4), 256, 0, stream>>>(core, out_w, out_b, (float*)d_out, NPIX, 256, 256);
}

// Round 2
// 195.475 us; speedup vs baseline: 1.3927x; 1.3927x over previous
//
#include <hip/hip_runtime.h>
#include <math.h>

#define NB   4
#define HH   64
#define WW   64
#define CCH  256
#define GG   8
#define CGC  32
#define HI   66
#define NPIX 16384
#define OMW  216   // 144 offsets + 72 mask logits

// ---------------- generic fp32 tiled GEMM ----------------
// C[M,Nn] = A[M,Kk] @ B[Kk,Nn] + bias
// MODE 0: out[row*Nn + col]
// MODE 1: out is xpad [N,66,66,256]; row is pixel index, stored at (h+1,w+1)
template<int MODE>
__global__ __launch_bounds__(256)
void gemm_f32(const float* __restrict__ A, const float* __restrict__ B,
              const float* __restrict__ bias, float* __restrict__ out,
              int M, int Nn, int Kk)
{
    __shared__ float As[16][64];
    __shared__ float Bs[16][64];
    const int tid = threadIdx.x;
    const int tm = tid >> 4, tn = tid & 15;
    const int row0 = blockIdx.x * 64, col0 = blockIdx.y * 64;

    const int lam = tid >> 2;          // 0..63  (A row within tile)
    const int lak = (tid & 3) << 2;    // 0,4,8,12 (A k within tile)
    const int lbk = tid >> 4;          // 0..15  (B k within tile)
    const int lbn = (tid & 15) << 2;   // 0..60  (B col within tile)

    float acc[4][4] = {};

    for (int kb = 0; kb < Kk; kb += 16) {
        float4 av = *reinterpret_cast<const float4*>(A + (size_t)(row0 + lam) * Kk + kb + lak);
        As[lak + 0][lam] = av.x;
        As[lak + 1][lam] = av.y;
        As[lak + 2][lam] = av.z;
        As[lak + 3][lam] = av.w;

        int bcol = col0 + lbn;
        float4 bv;
        const float* brow = B + (size_t)(kb + lbk) * Nn;
        if (bcol + 3 < Nn) {
            bv = *reinterpret_cast<const float4*>(brow + bcol);
        } else {
            bv.x = (bcol + 0 < Nn) ? brow[bcol + 0] : 0.f;
            bv.y = (bcol + 1 < Nn) ? brow[bcol + 1] : 0.f;
            bv.z = (bcol + 2 < Nn) ? brow[bcol + 2] : 0.f;
            bv.w = (bcol + 3 < Nn) ? brow[bcol + 3] : 0.f;
        }
        Bs[lbk][lbn + 0] = bv.x;
        Bs[lbk][lbn + 1] = bv.y;
        Bs[lbk][lbn + 2] = bv.z;
        Bs[lbk][lbn + 3] = bv.w;

        __syncthreads();
        #pragma unroll
        for (int k = 0; k < 16; ++k) {
            float a0 = As[k][tm * 4 + 0];
            float a1 = As[k][tm * 4 + 1];
            float a2 = As[k][tm * 4 + 2];
            float a3 = As[k][tm * 4 + 3];
            float b0 = Bs[k][tn * 4 + 0];
            float b1 = Bs[k][tn * 4 + 1];
            float b2 = Bs[k][tn * 4 + 2];
            float b3 = Bs[k][tn * 4 + 3];
            acc[0][0] += a0 * b0; acc[0][1] += a0 * b1; acc[0][2] += a0 * b2; acc[0][3] += a0 * b3;
            acc[1][0] += a1 * b0; acc[1][1] += a1 * b1; acc[1][2] += a1 * b2; acc[1][3] += a1 * b3;
            acc[2][0] += a2 * b0; acc[2][1] += a2 * b1; acc[2][2] += a2 * b2; acc[2][3] += a2 * b3;
            acc[3][0] += a3 * b0; acc[3][1] += a3 * b1; acc[3][2] += a3 * b2; acc[3][3] += a3 * b3;
        }
        __syncthreads();
    }

    #pragma unroll
    for (int i = 0; i < 4; ++i) {
        int row = row0 + tm * 4 + i;
        float* dst;
        if (MODE == 1) {
            int n = row >> 12;
            int hw = row & 4095;
            int h = hw >> 6, w = hw & 63;
            dst = out + (size_t)((n * HI + h + 1) * HI + (w + 1)) * CCH;
        } else {
            dst = out + (size_t)row * Nn;
        }
        #pragma unroll
        for (int j = 0; j < 4; ++j) {
            int col = col0 + tn * 4 + j;
            if (col < Nn) dst[col] = acc[i][j] + bias[col];
        }
    }
}

// ---------------- pack off_w|mask_w into one [256,216] matrix ----------------
__global__ __launch_bounds__(256)
void pack_offmask(const float* __restrict__ off_w, const float* __restrict__ off_b,
                  const float* __restrict__ mask_w, const float* __restrict__ mask_b,
                  float* __restrict__ W2, float* __restrict__ b2)
{
    int t = blockIdx.x * 256 + threadIdx.x;
    if (t < 256 * OMW) {
        int k = t / OMW, j = t % OMW;
        W2[t] = (j < 144) ? off_w[k * 144 + j] : mask_w[k * 72 + (j - 144)];
    }
    if (t < OMW) b2[t] = (t < 144) ? off_b[t] : mask_b[t - 144];
}

// ---------------- depthwise 3x3 + BN(inference) + SiLU ----------------
__global__ __launch_bounds__(256)
void dw_bn_silu(const float* __restrict__ x, const float* __restrict__ dwk,
                const float* __restrict__ bg, const float* __restrict__ bb,
                const float* __restrict__ bmv, const float* __restrict__ bvv,
                float* __restrict__ x1)
{
    int pix = blockIdx.x;
    int n = pix >> 12, hw = pix & 4095, h = hw >> 6, w = hw & 63;
    int c = threadIdx.x;
    float acc = 0.f;
    #pragma unroll
    for (int kh = 0; kh < 3; ++kh) {
        int hh = h + kh - 1;
        if (hh < 0 || hh >= HH) continue;
        #pragma unroll
        for (int kw = 0; kw < 3; ++kw) {
            int ww = w + kw - 1;
            if (ww < 0 || ww >= WW) continue;
            acc += x[(size_t)((n * HH + hh) * WW + ww) * CCH + c] * dwk[c * 9 + kh * 3 + kw];
        }
    }
    float y = bg[c] * (acc - bmv[c]) * rsqrtf(bvv[c] + 1e-5f) + bb[c];
    y = y / (1.f + expf(-y));
    x1[(size_t)pix * CCH + c] = y;
}

// ---------------- DCNv3 core: softmax + bilinear sampling ----------------
// One wave per pixel; lane = (group g = lane>>3, 4 channels c4 = (lane&7)*4).
// float4 gathers; softmax/weights amortized over 4 channels.
__global__ __launch_bounds__(256)
void dcn_sample(const float* __restrict__ xpad, const float* __restrict__ om,
                float* __restrict__ core)
{
    const int lane = threadIdx.x & 63;
    const int wid  = threadIdx.x >> 6;
    const int pix  = blockIdx.x * 4 + wid;
    const int n = pix >> 12, hw = pix & 4095, h = hw >> 6, w = hw & 63;
    const int g  = lane >> 3;
    const int c4 = (lane & 7) << 2;
    const float* __restrict__ omp = om + (size_t)pix * OMW;

    // per-group softmax over 9 points (redundant across the 8 lanes of the group)
    float lg[9], mx = -1e30f;
    #pragma unroll
    for (int p = 0; p < 9; ++p) { lg[p] = omp[144 + g * 9 + p]; mx = fmaxf(mx, lg[p]); }
    float s = 0.f;
    #pragma unroll
    for (int p = 0; p < 9; ++p) { lg[p] = __expf(lg[p] - mx); s += lg[p]; }
    const float inv = 1.f / s;

    const float* __restrict__ img = xpad + (size_t)n * HI * HI * CCH + g * CGC + c4;
    float ax = 0.f, ay = 0.f, az = 0.f, aw = 0.f;
    #pragma unroll
    for (int p = 0; p < 9; ++p) {
        float ox = omp[g * 18 + p * 2 + 0];
        float oy = omp[g * 18 + p * 2 + 1];
        // padded-image coords: center (w+1,h+1) + kernel offset + learned offset
        float xi = (float)(w + (p / 3)) + ox;
        float yi = (float)(h + (p % 3)) + oy;
        float x0f = floorf(xi), y0f = floorf(yi);
        int x0 = (int)x0f, y0 = (int)y0f;
        float fx = xi - x0f, fy = yi - y0f;
        float wgt = lg[p] * inv;
        float w00 = (1.f - fx) * (1.f - fy) * wgt;
        float w10 = fx * (1.f - fy) * wgt;
        float w01 = (1.f - fx) * fy * wgt;
        float w11 = fx * fy * wgt;
        const bool vx0 = (unsigned)x0 < HI, vx1 = (unsigned)(x0 + 1) < HI;
        const bool vy0 = (unsigned)y0 < HI, vy1 = (unsigned)(y0 + 1) < HI;
        if (vy0) {
            int rb = y0 * HI * CCH;   // y0 >= 0 here, int math safe
            if (vx0) {
                const float4 v = *reinterpret_cast<const float4*>(img + rb + x0 * CCH);
                ax += w00 * v.x; ay += w00 * v.y; az += w00 * v.z; aw += w00 * v.w;
            }
            if (vx1) {
                const float4 v = *reinterpret_cast<const float4*>(img + rb + (x0 + 1) * CCH);
                ax += w10 * v.x; ay += w10 * v.y; az += w10 * v.z; aw += w10 * v.w;
            }
        }
        if (vy1) {
            int rb = (y0 + 1) * HI * CCH;
            if (vx0) {
                const float4 v = *reinterpret_cast<const float4*>(img + rb + x0 * CCH);
                ax += w01 * v.x; ay += w01 * v.y; az += w01 * v.z; aw += w01 * v.w;
            }
            if (vx1) {
                const float4 v = *reinterpret_cast<const float4*>(img + rb + (x0 + 1) * CCH);
                ax += w11 * v.x; ay += w11 * v.y; az += w11 * v.z; aw += w11 * v.w;
            }
        }
    }
    float4 acc; acc.x = ax; acc.y = ay; acc.z = az; acc.w = aw;
    *reinterpret_cast<float4*>(core + (size_t)pix * CCH + g * CGC + c4) = acc;
}

extern "C" void kernel_launch(void* const* d_in, const int* in_sizes, int n_in,
                              void* d_out, int out_size, void* d_ws, size_t ws_size,
                              hipStream_t stream) {
    const float* x      = (const float*)d_in[0];
    const float* in_w   = (const float*)d_in[1];
    const float* in_b   = (const float*)d_in[2];
    const float* out_w  = (const float*)d_in[3];
    const float* out_b  = (const float*)d_in[4];
    const float* off_w  = (const float*)d_in[5];
    const float* off_b  = (const float*)d_in[6];
    const float* mask_w = (const float*)d_in[7];
    const float* mask_b = (const float*)d_in[8];
    const float* dw_k   = (const float*)d_in[9];
    const float* bn_g   = (const float*)d_in[10];
    const float* bn_b   = (const float*)d_in[11];
    const float* bn_m   = (const float*)d_in[12];
    const float* bn_v   = (const float*)d_in[13];

    float* ws   = (float*)d_ws;
    float* xpad = ws;                       // 4*66*66*256 = 4,460,544 floats
    float* x1   = xpad + 4460544;           // 16384*256 = 4,194,304 (reused as 'core')
    float* offm = x1 + 4194304;             // 16384*216 = 3,538,944
    float* W2   = offm + 3538944;           // 256*216 = 55,296
    float* b2   = W2 + 55296;               // 216
    float* core = x1;                       // alias: x1 dead after offm GEMM

    // zero the padded image (border ring must be 0 every call)
    hipMemsetAsync(xpad, 0, (size_t)4460544 * sizeof(float), stream);

    pack_offmask<<<(256 * OMW + 255) / 256, 256, 0, stream>>>(off_w, off_b, mask_w, mask_b, W2, b2);

    // 1) input projection -> padded image interior
    gemm_f32<1><<<dim3(NPIX / 64, 4), 256, 0, stream>>>(x, in_w, in_b, xpad, NPIX, 256, 256);

    // 2) depthwise conv + BN + SiLU
    dw_bn_silu<<<NPIX, 256, 0, stream>>>(x, dw_k, bn_g, bn_b, bn_m, bn_v, x1);

    // 3) offset + mask projection (fused GEMM, N=216)
    gemm_f32<0><<<dim3(NPIX / 64, (OMW + 63) / 64), 256, 0, stream>>>(x1, W2, b2, offm, NPIX, OMW, 256);

    // 4) deformable sampling (softmax in-register, wave-per-pixel, float4)
    dcn_sample<<<NPIX / 4, 256, 0, stream>>>(xpad, offm, core);

    // 5) output projection -> d_out
    gemm_f32<0><<<dim3(NPIX / 64, 4), 256, 0, stream>>>(core, out_w, out_b, (float*)d_out, NPIX, 256, 256);
}

// Round 3
// 110.324 us; speedup vs baseline: 2.4676x; 1.7718x over previous
//
#include <hip/hip_runtime.h>
#include <math.h>

#define NB   4
#define HH   64
#define WW   64
#define CCH  256
#define GG   8
#define CGC  32
#define HI   66
#define NPIX 16384
#define OMWS 256   // offm row stride: 144 off + 72 mask + 40 pad

typedef unsigned short ushort_t;
typedef __attribute__((ext_vector_type(8))) short short8;
typedef __attribute__((ext_vector_type(4))) float floatx4;

__device__ inline ushort_t f2bf(float f) {
    union { float f; unsigned u; } v; v.f = f;
    unsigned r = v.u + 0x7FFF + ((v.u >> 16) & 1);   // round-to-nearest-even
    return (ushort_t)(r >> 16);
}

__device__ inline void gload_lds16(const ushort_t* g, ushort_t* l) {
    __builtin_amdgcn_global_load_lds(
        (const __attribute__((address_space(1))) void*)g,
        (__attribute__((address_space(3))) void*)l, 16, 0, 0);
}

// ---------------- bf16 MFMA GEMM: C[M,256] = A[M,256] @ B[256,256] + bias ----
// A: bf16 [M][256] row-major. Bt: bf16 [n][k] (pre-transposed). out: fp32.
// MODE 0: out[row*256+col].  MODE 1: out is xpad [4,66,66,256], interior.
// 64x64 tile, 4 waves (2x2), each wave 32x32 via 2x2 frags of 16x16x32.
// LDS linear [64][64] bf16; 16B-granule XOR swizzle (pre-swizzled global src).
template<int MODE>
__global__ __launch_bounds__(256)
void gemm_mfma(const ushort_t* __restrict__ A, const ushort_t* __restrict__ Bt,
               const float* __restrict__ bias, float* __restrict__ out)
{
    __shared__ ushort_t As[64 * 64];
    __shared__ ushort_t Bs[64 * 64];
    const int tid  = threadIdx.x;
    const int lane = tid & 63, wid = tid >> 6;
    const int wr = wid >> 1, wc = wid & 1;
    const int q = lane >> 4, r = lane & 15;
    const int row0 = blockIdx.x * 64, col0 = blockIdx.y * 64;

    // staging: thread covers rows {srow, srow+32}, 16B granule sg (pre-swizzled)
    const int srow = tid >> 3;                     // 0..31
    const int sg   = (tid & 7) ^ (srow & 7);       // XOR swizzle, granule units
    const ushort_t* ga = A  + (size_t)(row0 + srow) * 256 + sg * 8;
    const ushort_t* gb = Bt + (size_t)(col0 + srow) * 256 + sg * 8;
    ushort_t* la = As + tid * 8;                   // linear dest, byte tid*16
    ushort_t* lb = Bs + tid * 8;

    floatx4 acc[2][2] = {};

    for (int kb = 0; kb < 4; ++kb) {
        gload_lds16(ga + kb * 64,            la);
        gload_lds16(ga + kb * 64 + 32 * 256, la + 32 * 64);
        gload_lds16(gb + kb * 64,            lb);
        gload_lds16(gb + kb * 64 + 32 * 256, lb + 32 * 64);
        __syncthreads();
        #pragma unroll
        for (int kk = 0; kk < 2; ++kk) {
            short8 af[2], bf[2];
            const int gsw = ((kk * 4 + q) ^ (r & 7)) * 8;  // swizzled k-granule
            #pragma unroll
            for (int m = 0; m < 2; ++m) {
                af[m] = *(const short8*)&As[(wr * 32 + m * 16 + r) * 64 + gsw];
                bf[m] = *(const short8*)&Bs[(wc * 32 + m * 16 + r) * 64 + gsw];
            }
            #pragma unroll
            for (int m = 0; m < 2; ++m)
                #pragma unroll
                for (int n = 0; n < 2; ++n)
                    acc[m][n] = __builtin_amdgcn_mfma_f32_16x16x32_bf16(
                                    af[m], bf[n], acc[m][n], 0, 0, 0);
        }
        __syncthreads();
    }

    #pragma unroll
    for (int m = 0; m < 2; ++m) {
        #pragma unroll
        for (int n = 0; n < 2; ++n) {
            #pragma unroll
            for (int j = 0; j < 4; ++j) {
                int row = row0 + wr * 32 + m * 16 + q * 4 + j;
                int col = col0 + wc * 32 + n * 16 + r;
                float v = acc[m][n][j] + bias[col];
                if (MODE == 1) {
                    int nn = row >> 12, hh = (row >> 6) & 63, www = row & 63;
                    out[(size_t)((nn * HI + hh + 1) * HI + (www + 1)) * CCH + col] = v;
                } else {
                    out[(size_t)row * 256 + col] = v;
                }
            }
        }
    }
}

// ---------------- fp32 -> bf16 cast (x) ----------------
__global__ __launch_bounds__(256)
void cvt_bf16(const float* __restrict__ in, ushort_t* __restrict__ out)
{
    int i = (blockIdx.x * 256 + threadIdx.x) * 8;
    float4 a = *reinterpret_cast<const float4*>(in + i);
    float4 b = *reinterpret_cast<const float4*>(in + i + 4);
    ushort_t v[8] = { f2bf(a.x), f2bf(a.y), f2bf(a.z), f2bf(a.w),
                      f2bf(b.x), f2bf(b.y), f2bf(b.z), f2bf(b.w) };
    *reinterpret_cast<short8*>(out + i) = *reinterpret_cast<short8*>(v);
}

// ---------------- pack transposed bf16 weights + fused off/mask ----------------
__global__ __launch_bounds__(256)
void pack_weights(const float* __restrict__ in_w, const float* __restrict__ out_w,
                  const float* __restrict__ off_w, const float* __restrict__ mask_w,
                  const float* __restrict__ off_b, const float* __restrict__ mask_b,
                  ushort_t* __restrict__ WtIn, ushort_t* __restrict__ WtOut,
                  ushort_t* __restrict__ W2t, float* __restrict__ b2)
{
    int n = blockIdx.x, k = threadIdx.x;
    WtIn [n * 256 + k] = f2bf(in_w [k * 256 + n]);
    WtOut[n * 256 + k] = f2bf(out_w[k * 256 + n]);
    float w2 = (n < 144) ? off_w[k * 144 + n]
             : (n < 216) ? mask_w[k * 72 + (n - 144)] : 0.f;
    W2t[n * 256 + k] = f2bf(w2);
    if (k == 0) b2[n] = (n < 144) ? off_b[n] : (n < 216) ? mask_b[n - 144] : 0.f;
}

// ---------------- depthwise 3x3 + BN(inference) + SiLU -> bf16 ----------------
__global__ __launch_bounds__(256)
void dw_bn_silu(const float* __restrict__ x, const float* __restrict__ dwk,
                const float* __restrict__ bg, const float* __restrict__ bb,
                const float* __restrict__ bmv, const float* __restrict__ bvv,
                ushort_t* __restrict__ x1b)
{
    int pix = blockIdx.x;
    int n = pix >> 12, hw = pix & 4095, h = hw >> 6, w = hw & 63;
    int c = threadIdx.x;
    float acc = 0.f;
    #pragma unroll
    for (int kh = 0; kh < 3; ++kh) {
        int hh = h + kh - 1;
        if (hh < 0 || hh >= HH) continue;
        #pragma unroll
        for (int kw = 0; kw < 3; ++kw) {
            int ww = w + kw - 1;
            if (ww < 0 || ww >= WW) continue;
            acc += x[(size_t)((n * HH + hh) * WW + ww) * CCH + c] * dwk[c * 9 + kh * 3 + kw];
        }
    }
    float y = bg[c] * (acc - bmv[c]) * rsqrtf(bvv[c] + 1e-5f) + bb[c];
    y = y / (1.f + __expf(-y));
    x1b[(size_t)pix * CCH + c] = f2bf(y);
}

// ---------------- DCNv3 core: softmax + bilinear sampling -> bf16 ----------------
__global__ __launch_bounds__(256)
void dcn_sample(const float* __restrict__ xpad, const float* __restrict__ om,
                ushort_t* __restrict__ coreb)
{
    const int lane = threadIdx.x & 63;
    const int wid  = threadIdx.x >> 6;
    const int pix  = blockIdx.x * 4 + wid;
    const int n = pix >> 12, hw = pix & 4095, h = hw >> 6, w = hw & 63;
    const int g  = lane >> 3;
    const int c4 = (lane & 7) << 2;
    const float* __restrict__ omp = om + (size_t)pix * OMWS;

    float lg[9], mx = -1e30f;
    #pragma unroll
    for (int p = 0; p < 9; ++p) { lg[p] = omp[144 + g * 9 + p]; mx = fmaxf(mx, lg[p]); }
    float s = 0.f;
    #pragma unroll
    for (int p = 0; p < 9; ++p) { lg[p] = __expf(lg[p] - mx); s += lg[p]; }
    const float inv = 1.f / s;

    const float* __restrict__ img = xpad + (size_t)n * HI * HI * CCH + g * CGC + c4;
    float ax = 0.f, ay = 0.f, az = 0.f, aw = 0.f;
    #pragma unroll
    for (int p = 0; p < 9; ++p) {
        float ox = omp[g * 18 + p * 2 + 0];
        float oy = omp[g * 18 + p * 2 + 1];
        float xi = (float)(w + (p / 3)) + ox;
        float yi = (float)(h + (p % 3)) + oy;
        float x0f = floorf(xi), y0f = floorf(yi);
        int x0 = (int)x0f, y0 = (int)y0f;
        float fx = xi - x0f, fy = yi - y0f;
        float wgt = lg[p] * inv;
        float w00 = (1.f - fx) * (1.f - fy) * wgt;
        float w10 = fx * (1.f - fy) * wgt;
        float w01 = (1.f - fx) * fy * wgt;
        float w11 = fx * fy * wgt;
        const bool vx0 = (unsigned)x0 < HI, vx1 = (unsigned)(x0 + 1) < HI;
        const bool vy0 = (unsigned)y0 < HI, vy1 = (unsigned)(y0 + 1) < HI;
        if (vy0) {
            int rb = y0 * HI * CCH;
            if (vx0) { const float4 v = *reinterpret_cast<const float4*>(img + rb + x0 * CCH);
                       ax += w00 * v.x; ay += w00 * v.y; az += w00 * v.z; aw += w00 * v.w; }
            if (vx1) { const float4 v = *reinterpret_cast<const float4*>(img + rb + (x0 + 1) * CCH);
                       ax += w10 * v.x; ay += w10 * v.y; az += w10 * v.z; aw += w10 * v.w; }
        }
        if (vy1) {
            int rb = (y0 + 1) * HI * CCH;
            if (vx0) { const float4 v = *reinterpret_cast<const float4*>(img + rb + x0 * CCH);
                       ax += w01 * v.x; ay += w01 * v.y; az += w01 * v.z; aw += w01 * v.w; }
            if (vx1) { const float4 v = *reinterpret_cast<const float4*>(img + rb + (x0 + 1) * CCH);
                       ax += w11 * v.x; ay += w11 * v.y; az += w11 * v.z; aw += w11 * v.w; }
        }
    }
    ushort_t o[4] = { f2bf(ax), f2bf(ay), f2bf(az), f2bf(aw) };
    *reinterpret_cast<ushort4*>(coreb + (size_t)pix * CCH + g * CGC + c4) =
        *reinterpret_cast<ushort4*>(o);
}

extern "C" void kernel_launch(void* const* d_in, const int* in_sizes, int n_in,
                              void* d_out, int out_size, void* d_ws, size_t ws_size,
                              hipStream_t stream) {
    const float* x      = (const float*)d_in[0];
    const float* in_w   = (const float*)d_in[1];
    const float* in_b   = (const float*)d_in[2];
    const float* out_w  = (const float*)d_in[3];
    const float* out_b  = (const float*)d_in[4];
    const float* off_w  = (const float*)d_in[5];
    const float* off_b  = (const float*)d_in[6];
    const float* mask_w = (const float*)d_in[7];
    const float* mask_b = (const float*)d_in[8];
    const float* dw_k   = (const float*)d_in[9];
    const float* bn_g   = (const float*)d_in[10];
    const float* bn_b   = (const float*)d_in[11];
    const float* bn_m   = (const float*)d_in[12];
    const float* bn_v   = (const float*)d_in[13];

    float* ws = (float*)d_ws;
    float*    xpad  = ws;                                  // 4,460,544 f
    float*    offm  = xpad + 4460544;                      // 16384*256 f
    ushort_t* xb    = (ushort_t*)(offm + 4194304);         // 4,194,304 us
    ushort_t* x1b   = xb + 4194304;
    ushort_t* coreb = x1b + 4194304;
    ushort_t* WtIn  = coreb + 4194304;                     // 65,536 us
    ushort_t* WtOut = WtIn + 65536;
    ushort_t* W2t   = WtOut + 65536;
    float*    b2    = (float*)(W2t + 65536);               // 256 f

    // zero the padded image (border ring must be 0 every call)
    hipMemsetAsync(xpad, 0, (size_t)4460544 * sizeof(float), stream);

    pack_weights<<<256, 256, 0, stream>>>(in_w, out_w, off_w, mask_w, off_b, mask_b,
                                          WtIn, WtOut, W2t, b2);
    cvt_bf16<<<NPIX * CCH / (256 * 8), 256, 0, stream>>>(x, xb);

    // 1) input projection -> padded image interior (fp32 out)
    gemm_mfma<1><<<dim3(NPIX / 64, 4), 256, 0, stream>>>(xb, WtIn, in_b, xpad);

    // 2) depthwise conv + BN + SiLU -> bf16
    dw_bn_silu<<<NPIX, 256, 0, stream>>>(x, dw_k, bn_g, bn_b, bn_m, bn_v, x1b);

    // 3) offset + mask projection (fused, N padded to 256)
    gemm_mfma<0><<<dim3(NPIX / 64, 4), 256, 0, stream>>>(x1b, W2t, b2, offm);

    // 4) deformable sampling (softmax in-register, wave-per-pixel, float4)
    dcn_sample<<<NPIX / 4, 256, 0, stream>>>(xpad, offm, coreb);

    // 5) output projection -> d_out
    gemm_mfma<0><<<dim3(NPIX / 64, 4), 256, 0, stream>>>(coreb, WtOut, out_b, (float*)d_out);
}

// Round 4
// 103.129 us; speedup vs baseline: 2.6398x; 1.0698x over previous
//
#include <hip/hip_runtime.h>
#include <math.h>

#define NB   4
#define HH   64
#define WW   64
#define CCH  256
#define GG   8
#define CGC  32
#define HI   66
#define NPIX 16384
#define OMWS 256   // offm row stride: 144 off + 72 mask + 40 pad

typedef unsigned short ushort_t;
typedef __attribute__((ext_vector_type(8))) short short8;
typedef __attribute__((ext_vector_type(4))) float floatx4;

__device__ inline ushort_t f2bf(float f) {
    union { float f; unsigned u; } v; v.f = f;
    unsigned r = v.u + 0x7FFF + ((v.u >> 16) & 1);   // round-to-nearest-even
    return (ushort_t)(r >> 16);
}

__device__ inline void gload_lds16(const ushort_t* g, ushort_t* l) {
    __builtin_amdgcn_global_load_lds(
        (const __attribute__((address_space(1))) void*)g,
        (__attribute__((address_space(3))) void*)l, 16, 0, 0);
}

// ---------------- bf16 MFMA GEMM: C[M,256] = A[M,256] @ B[256,256] + bias ----
// A: bf16 [M][256] row-major. Bt: bf16 [n][k] (pre-transposed). out: fp32.
// MODE 0: out[row*256+col].  MODE 1: out is xpad [4,66,66,256], interior.
// 64x64 tile, 4 waves (2x2), each wave 32x32 via 2x2 frags of 16x16x32.
// LDS linear [64][64] bf16; 16B-granule XOR swizzle (pre-swizzled global src).
template<int MODE>
__global__ __launch_bounds__(256)
void gemm_mfma(const ushort_t* __restrict__ A, const ushort_t* __restrict__ Bt,
               const float* __restrict__ bias, float* __restrict__ out)
{
    __shared__ ushort_t As[64 * 64];
    __shared__ ushort_t Bs[64 * 64];
    const int tid  = threadIdx.x;
    const int lane = tid & 63, wid = tid >> 6;
    const int wr = wid >> 1, wc = wid & 1;
    const int q = lane >> 4, r = lane & 15;
    const int row0 = blockIdx.x * 64, col0 = blockIdx.y * 64;

    // staging: thread covers rows {srow, srow+32}, 16B granule sg (pre-swizzled)
    const int srow = tid >> 3;                     // 0..31
    const int sg   = (tid & 7) ^ (srow & 7);       // XOR swizzle, granule units
    const ushort_t* ga = A  + (size_t)(row0 + srow) * 256 + sg * 8;
    const ushort_t* gb = Bt + (size_t)(col0 + srow) * 256 + sg * 8;
    ushort_t* la = As + tid * 8;                   // linear dest, byte tid*16
    ushort_t* lb = Bs + tid * 8;

    floatx4 acc[2][2] = {};

    for (int kb = 0; kb < 4; ++kb) {
        gload_lds16(ga + kb * 64,            la);
        gload_lds16(ga + kb * 64 + 32 * 256, la + 32 * 64);
        gload_lds16(gb + kb * 64,            lb);
        gload_lds16(gb + kb * 64 + 32 * 256, lb + 32 * 64);
        __syncthreads();
        #pragma unroll
        for (int kk = 0; kk < 2; ++kk) {
            short8 af[2], bf[2];
            const int gsw = ((kk * 4 + q) ^ (r & 7)) * 8;  // swizzled k-granule
            #pragma unroll
            for (int m = 0; m < 2; ++m) {
                af[m] = *(const short8*)&As[(wr * 32 + m * 16 + r) * 64 + gsw];
                bf[m] = *(const short8*)&Bs[(wc * 32 + m * 16 + r) * 64 + gsw];
            }
            #pragma unroll
            for (int m = 0; m < 2; ++m)
                #pragma unroll
                for (int n = 0; n < 2; ++n)
                    acc[m][n] = __builtin_amdgcn_mfma_f32_16x16x32_bf16(
                                    af[m], bf[n], acc[m][n], 0, 0, 0);
        }
        __syncthreads();
    }

    #pragma unroll
    for (int m = 0; m < 2; ++m) {
        #pragma unroll
        for (int n = 0; n < 2; ++n) {
            #pragma unroll
            for (int j = 0; j < 4; ++j) {
                int row = row0 + wr * 32 + m * 16 + q * 4 + j;
                int col = col0 + wc * 32 + n * 16 + r;
                float v = acc[m][n][j] + bias[col];
                if (MODE == 1) {
                    int nn = row >> 12, hh = (row >> 6) & 63, www = row & 63;
                    out[(size_t)((nn * HI + hh + 1) * HI + (www + 1)) * CCH + col] = v;
                } else {
                    out[(size_t)row * 256 + col] = v;
                }
            }
        }
    }
}

// ---------------- zero only the pad ring of xpad ----------------
// 4 images x 260 ring pixels; block = 256 channels.
__global__ __launch_bounds__(256)
void zero_ring(float* __restrict__ xpad)
{
    int t = blockIdx.x;
    int n = t / 260, rp = t % 260;
    int h, w;
    if (rp < 66)       { h = 0;              w = rp; }
    else if (rp < 132) { h = 65;             w = rp - 66; }
    else if (rp < 196) { h = 1 + (rp - 132); w = 0; }
    else               { h = 1 + (rp - 196); w = 65; }
    xpad[(size_t)((n * HI + h) * HI + w) * CCH + threadIdx.x] = 0.f;
}

// ---------------- pack transposed bf16 weights + fused off/mask ----------------
__global__ __launch_bounds__(256)
void pack_weights(const float* __restrict__ in_w, const float* __restrict__ out_w,
                  const float* __restrict__ off_w, const float* __restrict__ mask_w,
                  const float* __restrict__ off_b, const float* __restrict__ mask_b,
                  ushort_t* __restrict__ WtIn, ushort_t* __restrict__ WtOut,
                  ushort_t* __restrict__ W2t, float* __restrict__ b2)
{
    int n = blockIdx.x, k = threadIdx.x;
    WtIn [n * 256 + k] = f2bf(in_w [k * 256 + n]);
    WtOut[n * 256 + k] = f2bf(out_w[k * 256 + n]);
    float w2 = (n < 144) ? off_w[k * 144 + n]
             : (n < 216) ? mask_w[k * 72 + (n - 144)] : 0.f;
    W2t[n * 256 + k] = f2bf(w2);
    if (k == 0) b2[n] = (n < 144) ? off_b[n] : (n < 216) ? mask_b[n - 144] : 0.f;
}

// ---------------- depthwise 3x3 + BN + SiLU -> bf16 x1b, plus cast x -> xb ----
__global__ __launch_bounds__(256)
void dw_bn_silu(const float* __restrict__ x, const float* __restrict__ dwk,
                const float* __restrict__ bg, const float* __restrict__ bb,
                const float* __restrict__ bmv, const float* __restrict__ bvv,
                ushort_t* __restrict__ x1b, ushort_t* __restrict__ xb)
{
    int pix = blockIdx.x;
    int n = pix >> 12, hw = pix & 4095, h = hw >> 6, w = hw & 63;
    int c = threadIdx.x;

    float cv = x[(size_t)pix * CCH + c];          // center tap
    xb[(size_t)pix * CCH + c] = f2bf(cv);         // free bf16 cast of x

    float acc = cv * dwk[c * 9 + 4];
    #pragma unroll
    for (int kh = 0; kh < 3; ++kh) {
        int hh = h + kh - 1;
        if (hh < 0 || hh >= HH) continue;
        #pragma unroll
        for (int kw = 0; kw < 3; ++kw) {
            if (kh == 1 && kw == 1) continue;
            int ww = w + kw - 1;
            if (ww < 0 || ww >= WW) continue;
            acc += x[(size_t)((n * HH + hh) * WW + ww) * CCH + c] * dwk[c * 9 + kh * 3 + kw];
        }
    }
    float y = bg[c] * (acc - bmv[c]) * rsqrtf(bvv[c] + 1e-5f) + bb[c];
    y = y / (1.f + __expf(-y));
    x1b[(size_t)pix * CCH + c] = f2bf(y);
}

// ---------------- DCNv3 core: softmax + bilinear sampling -> bf16 ----------------
__global__ __launch_bounds__(256)
void dcn_sample(const float* __restrict__ xpad, const float* __restrict__ om,
                ushort_t* __restrict__ coreb)
{
    const int lane = threadIdx.x & 63;
    const int wid  = threadIdx.x >> 6;
    const int pix  = blockIdx.x * 4 + wid;
    const int n = pix >> 12, hw = pix & 4095, h = hw >> 6, w = hw & 63;
    const int g  = lane >> 3;
    const int c4 = (lane & 7) << 2;
    const float* __restrict__ omp = om + (size_t)pix * OMWS;

    float lg[9], mx = -1e30f;
    #pragma unroll
    for (int p = 0; p < 9; ++p) { lg[p] = omp[144 + g * 9 + p]; mx = fmaxf(mx, lg[p]); }
    float s = 0.f;
    #pragma unroll
    for (int p = 0; p < 9; ++p) { lg[p] = __expf(lg[p] - mx); s += lg[p]; }
    const float inv = 1.f / s;

    const float* __restrict__ img = xpad + (size_t)n * HI * HI * CCH + g * CGC + c4;
    float ax = 0.f, ay = 0.f, az = 0.f, aw = 0.f;
    #pragma unroll
    for (int p = 0; p < 9; ++p) {
        float ox = omp[g * 18 + p * 2 + 0];
        float oy = omp[g * 18 + p * 2 + 1];
        float xi = (float)(w + (p / 3)) + ox;
        float yi = (float)(h + (p % 3)) + oy;
        float x0f = floorf(xi), y0f = floorf(yi);
        int x0 = (int)x0f, y0 = (int)y0f;
        float fx = xi - x0f, fy = yi - y0f;
        float wgt = lg[p] * inv;
        float w00 = (1.f - fx) * (1.f - fy) * wgt;
        float w10 = fx * (1.f - fy) * wgt;
        float w01 = (1.f - fx) * fy * wgt;
        float w11 = fx * fy * wgt;
        const bool vx0 = (unsigned)x0 < HI, vx1 = (unsigned)(x0 + 1) < HI;
        const bool vy0 = (unsigned)y0 < HI, vy1 = (unsigned)(y0 + 1) < HI;
        if (vy0) {
            int rb = y0 * HI * CCH;
            if (vx0) { const float4 v = *reinterpret_cast<const float4*>(img + rb + x0 * CCH);
                       ax += w00 * v.x; ay += w00 * v.y; az += w00 * v.z; aw += w00 * v.w; }
            if (vx1) { const float4 v = *reinterpret_cast<const float4*>(img + rb + (x0 + 1) * CCH);
                       ax += w10 * v.x; ay += w10 * v.y; az += w10 * v.z; aw += w10 * v.w; }
        }
        if (vy1) {
            int rb = (y0 + 1) * HI * CCH;
            if (vx0) { const float4 v = *reinterpret_cast<const float4*>(img + rb + x0 * CCH);
                       ax += w01 * v.x; ay += w01 * v.y; az += w01 * v.z; aw += w01 * v.w; }
            if (vx1) { const float4 v = *reinterpret_cast<const float4*>(img + rb + (x0 + 1) * CCH);
                       ax += w11 * v.x; ay += w11 * v.y; az += w11 * v.z; aw += w11 * v.w; }
        }
    }
    ushort_t o[4] = { f2bf(ax), f2bf(ay), f2bf(az), f2bf(aw) };
    *reinterpret_cast<ushort4*>(coreb + (size_t)pix * CCH + g * CGC + c4) =
        *reinterpret_cast<ushort4*>(o);
}

extern "C" void kernel_launch(void* const* d_in, const int* in_sizes, int n_in,
                              void* d_out, int out_size, void* d_ws, size_t ws_size,
                              hipStream_t stream) {
    const float* x      = (const float*)d_in[0];
    const float* in_w   = (const float*)d_in[1];
    const float* in_b   = (const float*)d_in[2];
    const float* out_w  = (const float*)d_in[3];
    const float* out_b  = (const float*)d_in[4];
    const float* off_w  = (const float*)d_in[5];
    const float* off_b  = (const float*)d_in[6];
    const float* mask_w = (const float*)d_in[7];
    const float* mask_b = (const float*)d_in[8];
    const float* dw_k   = (const float*)d_in[9];
    const float* bn_g   = (const float*)d_in[10];
    const float* bn_b   = (const float*)d_in[11];
    const float* bn_m   = (const float*)d_in[12];
    const float* bn_v   = (const float*)d_in[13];

    float* ws = (float*)d_ws;
    float*    xpad  = ws;                                  // 4,460,544 f
    float*    offm  = xpad + 4460544;                      // 16384*256 f
    ushort_t* xb    = (ushort_t*)(offm + 4194304);         // 4,194,304 us
    ushort_t* x1b   = xb + 4194304;
    ushort_t* coreb = x1b + 4194304;
    ushort_t* WtIn  = coreb + 4194304;                     // 65,536 us
    ushort_t* WtOut = WtIn + 65536;
    ushort_t* W2t   = WtOut + 65536;
    float*    b2    = (float*)(W2t + 65536);               // 256 f

    // zero only the pad ring (interior fully overwritten by gemm_mfma<1>)
    zero_ring<<<NB * 260, 256, 0, stream>>>(xpad);

    pack_weights<<<256, 256, 0, stream>>>(in_w, out_w, off_w, mask_w, off_b, mask_b,
                                          WtIn, WtOut, W2t, b2);

    // 1) depthwise conv + BN + SiLU -> x1b, and cast x -> xb (fused)
    dw_bn_silu<<<NPIX, 256, 0, stream>>>(x, dw_k, bn_g, bn_b, bn_m, bn_v, x1b, xb);

    // 2) input projection -> padded image interior (fp32 out)
    gemm_mfma<1><<<dim3(NPIX / 64, 4), 256, 0, stream>>>(xb, WtIn, in_b, xpad);

    // 3) offset + mask projection (fused, N padded to 256)
    gemm_mfma<0><<<dim3(NPIX / 64, 4), 256, 0, stream>>>(x1b, W2t, b2, offm);

    // 4) deformable sampling (softmax in-register, wave-per-pixel, float4)
    dcn_sample<<<NPIX / 4, 256, 0, stream>>>(xpad, offm, coreb);

    // 5) output projection -> d_out
    gemm_mfma<0><<<dim3(NPIX / 64, 4), 256, 0, stream>>>(coreb, WtOut, out_b, (float*)d_out);
}

// Round 5
// 82.402 us; speedup vs baseline: 3.3037x; 1.2515x over previous
//
#include <hip/hip_runtime.h>
#include <math.h>

#define NB   4
#define HH   64
#define WW   64
#define CCH  256
#define GG   8
#define CGC  32
#define HI   66
#define NPIX 16384
#define OMWS 256   // offm row stride: 144 off + 72 mask + 40 pad

typedef unsigned short ushort_t;
typedef __attribute__((ext_vector_type(8))) short short8;
typedef __attribute__((ext_vector_type(4))) float floatx4;

__device__ inline ushort_t f2bf(float f) {
    union { float f; unsigned u; } v; v.f = f;
    unsigned r = v.u + 0x7FFF + ((v.u >> 16) & 1);   // round-to-nearest-even
    return (ushort_t)(r >> 16);
}

__device__ inline void gload_lds16(const ushort_t* g, ushort_t* l) {
    __builtin_amdgcn_global_load_lds(
        (const __attribute__((address_space(1))) void*)g,
        (__attribute__((address_space(3))) void*)l, 16, 0, 0);
}

// ---------------- bf16 MFMA GEMM: C[M,256] = A[M,256] @ B[256,256] + bias ----
// A: bf16 [M][256] row-major. Bt: bf16 [n][k] (pre-transposed). out: fp32.
// MODE 0: out[row*256+col].  MODE 1: out is xpad [4,66,66,256], interior.
template<int MODE>
__global__ __launch_bounds__(256)
void gemm_mfma(const ushort_t* __restrict__ A, const ushort_t* __restrict__ Bt,
               const float* __restrict__ bias, float* __restrict__ out)
{
    __shared__ ushort_t As[64 * 64];
    __shared__ ushort_t Bs[64 * 64];
    const int tid  = threadIdx.x;
    const int lane = tid & 63, wid = tid >> 6;
    const int wr = wid >> 1, wc = wid & 1;
    const int q = lane >> 4, r = lane & 15;
    const int row0 = blockIdx.x * 64, col0 = blockIdx.y * 64;

    const int srow = tid >> 3;                     // 0..31
    const int sg   = (tid & 7) ^ (srow & 7);       // XOR swizzle, granule units
    const ushort_t* ga = A  + (size_t)(row0 + srow) * 256 + sg * 8;
    const ushort_t* gb = Bt + (size_t)(col0 + srow) * 256 + sg * 8;
    ushort_t* la = As + tid * 8;
    ushort_t* lb = Bs + tid * 8;

    floatx4 acc[2][2] = {};

    for (int kb = 0; kb < 4; ++kb) {
        gload_lds16(ga + kb * 64,            la);
        gload_lds16(ga + kb * 64 + 32 * 256, la + 32 * 64);
        gload_lds16(gb + kb * 64,            lb);
        gload_lds16(gb + kb * 64 + 32 * 256, lb + 32 * 64);
        __syncthreads();
        #pragma unroll
        for (int kk = 0; kk < 2; ++kk) {
            short8 af[2], bf[2];
            const int gsw = ((kk * 4 + q) ^ (r & 7)) * 8;
            #pragma unroll
            for (int m = 0; m < 2; ++m) {
                af[m] = *(const short8*)&As[(wr * 32 + m * 16 + r) * 64 + gsw];
                bf[m] = *(const short8*)&Bs[(wc * 32 + m * 16 + r) * 64 + gsw];
            }
            #pragma unroll
            for (int m = 0; m < 2; ++m)
                #pragma unroll
                for (int n = 0; n < 2; ++n)
                    acc[m][n] = __builtin_amdgcn_mfma_f32_16x16x32_bf16(
                                    af[m], bf[n], acc[m][n], 0, 0, 0);
        }
        __syncthreads();
    }

    #pragma unroll
    for (int m = 0; m < 2; ++m) {
        #pragma unroll
        for (int n = 0; n < 2; ++n) {
            #pragma unroll
            for (int j = 0; j < 4; ++j) {
                int row = row0 + wr * 32 + m * 16 + q * 4 + j;
                int col = col0 + wc * 32 + n * 16 + r;
                float v = acc[m][n][j] + bias[col];
                if (MODE == 1) {
                    int nn = row >> 12, hh = (row >> 6) & 63, www = row & 63;
                    out[(size_t)((nn * HI + hh + 1) * HI + (www + 1)) * CCH + col] = v;
                } else {
                    out[(size_t)row * 256 + col] = v;
                }
            }
        }
    }
}

// ---------------- zero only the pad ring of xpad ----------------
__global__ __launch_bounds__(256)
void zero_ring(float* __restrict__ xpad)
{
    int t = blockIdx.x;
    int n = t / 260, rp = t % 260;
    int h, w;
    if (rp < 66)       { h = 0;              w = rp; }
    else if (rp < 132) { h = 65;             w = rp - 66; }
    else if (rp < 196) { h = 1 + (rp - 132); w = 0; }
    else               { h = 1 + (rp - 196); w = 65; }
    xpad[(size_t)((n * HI + h) * HI + w) * CCH + threadIdx.x] = 0.f;
}

// ---------------- pack weights: bf16 transposed GEMM weights, tap-major dwk,
// ---------------- folded BN affine, fused off/mask ----------------
__global__ __launch_bounds__(256)
void pack_weights(const float* __restrict__ in_w, const float* __restrict__ out_w,
                  const float* __restrict__ off_w, const float* __restrict__ mask_w,
                  const float* __restrict__ off_b, const float* __restrict__ mask_b,
                  const float* __restrict__ dw_k, const float* __restrict__ bn_g,
                  const float* __restrict__ bn_b, const float* __restrict__ bn_m,
                  const float* __restrict__ bn_v,
                  ushort_t* __restrict__ WtIn, ushort_t* __restrict__ WtOut,
                  ushort_t* __restrict__ W2t, float* __restrict__ b2,
                  float* __restrict__ dwkT, float* __restrict__ bnS,
                  float* __restrict__ bnB)
{
    int n = blockIdx.x, k = threadIdx.x;
    WtIn [n * 256 + k] = f2bf(in_w [k * 256 + n]);
    WtOut[n * 256 + k] = f2bf(out_w[k * 256 + n]);
    float w2 = (n < 144) ? off_w[k * 144 + n]
             : (n < 216) ? mask_w[k * 72 + (n - 144)] : 0.f;
    W2t[n * 256 + k] = f2bf(w2);
    if (k == 0) b2[n] = (n < 144) ? off_b[n] : (n < 216) ? mask_b[n - 144] : 0.f;
    if (k < 9) dwkT[k * 256 + n] = dw_k[n * 9 + k];   // tap-major
    if (k == 9) {
        float s = bn_g[n] * rsqrtf(bn_v[n] + 1e-5f);
        bnS[n] = s;
        bnB[n] = bn_b[n] - bn_m[n] * s;
    }
}

// ---------------- depthwise 3x3 + BN + SiLU -> bf16 x1b, plus cast x -> xb ----
// one wave per pixel, lane owns 4 channels (float4)
__global__ __launch_bounds__(256)
void dw_bn_silu(const float* __restrict__ x, const float* __restrict__ dwkT,
                const float* __restrict__ bnS, const float* __restrict__ bnB,
                ushort_t* __restrict__ x1b, ushort_t* __restrict__ xb)
{
    const int lane = threadIdx.x & 63, wid = threadIdx.x >> 6;
    const int pix = blockIdx.x * 4 + wid;
    const int n = pix >> 12, hw = pix & 4095, h = hw >> 6, w = hw & 63;
    const int c4 = lane << 2;

    const float4 cv = *reinterpret_cast<const float4*>(x + (size_t)pix * CCH + c4);
    ushort_t xo[4] = { f2bf(cv.x), f2bf(cv.y), f2bf(cv.z), f2bf(cv.w) };
    *reinterpret_cast<ushort4*>(xb + (size_t)pix * CCH + c4) = *reinterpret_cast<ushort4*>(xo);

    const float4 kc = *reinterpret_cast<const float4*>(dwkT + 4 * 256 + c4);
    float ax = cv.x * kc.x, ay = cv.y * kc.y, az = cv.z * kc.z, aw = cv.w * kc.w;

    #pragma unroll
    for (int tap = 0; tap < 9; ++tap) {
        if (tap == 4) continue;
        int hh = h + tap / 3 - 1, ww = w + tap % 3 - 1;
        if ((unsigned)hh < HH && (unsigned)ww < WW) {
            const float4 v = *reinterpret_cast<const float4*>(
                x + (size_t)((n * HH + hh) * WW + ww) * CCH + c4);
            const float4 kk = *reinterpret_cast<const float4*>(dwkT + tap * 256 + c4);
            ax += v.x * kk.x; ay += v.y * kk.y; az += v.z * kk.z; aw += v.w * kk.w;
        }
    }
    const float4 s = *reinterpret_cast<const float4*>(bnS + c4);
    const float4 b = *reinterpret_cast<const float4*>(bnB + c4);
    float yx = ax * s.x + b.x, yy = ay * s.y + b.y;
    float yz = az * s.z + b.z, yw = aw * s.w + b.w;
    yx = yx / (1.f + __expf(-yx));
    yy = yy / (1.f + __expf(-yy));
    yz = yz / (1.f + __expf(-yz));
    yw = yw / (1.f + __expf(-yw));
    ushort_t o[4] = { f2bf(yx), f2bf(yy), f2bf(yz), f2bf(yw) };
    *reinterpret_cast<ushort4*>(x1b + (size_t)pix * CCH + c4) = *reinterpret_cast<ushort4*>(o);
}

// ---------------- DCNv3 core: softmax + bilinear sampling -> bf16 ----------------
__global__ __launch_bounds__(256)
void dcn_sample(const float* __restrict__ xpad, const float* __restrict__ om,
                ushort_t* __restrict__ coreb)
{
    const int lane = threadIdx.x & 63;
    const int wid  = threadIdx.x >> 6;
    const int pix  = blockIdx.x * 4 + wid;
    const int n = pix >> 12, hw = pix & 4095, h = hw >> 6, w = hw & 63;
    const int g  = lane >> 3;
    const int c4 = (lane & 7) << 2;
    const float* __restrict__ omp = om + (size_t)pix * OMWS;

    float lg[9], mx = -1e30f;
    #pragma unroll
    for (int p = 0; p < 9; ++p) { lg[p] = omp[144 + g * 9 + p]; mx = fmaxf(mx, lg[p]); }
    float s = 0.f;
    #pragma unroll
    for (int p = 0; p < 9; ++p) { lg[p] = __expf(lg[p] - mx); s += lg[p]; }
    const float inv = 1.f / s;

    const float* __restrict__ img = xpad + (size_t)n * HI * HI * CCH + g * CGC + c4;
    float ax = 0.f, ay = 0.f, az = 0.f, aw = 0.f;
    #pragma unroll
    for (int p = 0; p < 9; ++p) {
        float ox = omp[g * 18 + p * 2 + 0];
        float oy = omp[g * 18 + p * 2 + 1];
        float xi = (float)(w + (p / 3)) + ox;
        float yi = (float)(h + (p % 3)) + oy;
        float x0f = floorf(xi), y0f = floorf(yi);
        int x0 = (int)x0f, y0 = (int)y0f;
        float fx = xi - x0f, fy = yi - y0f;
        float wgt = lg[p] * inv;
        float w00 = (1.f - fx) * (1.f - fy) * wgt;
        float w10 = fx * (1.f - fy) * wgt;
        float w01 = (1.f - fx) * fy * wgt;
        float w11 = fx * fy * wgt;
        const bool vx0 = (unsigned)x0 < HI, vx1 = (unsigned)(x0 + 1) < HI;
        const bool vy0 = (unsigned)y0 < HI, vy1 = (unsigned)(y0 + 1) < HI;
        if (vy0) {
            int rb = y0 * HI * CCH;
            if (vx0) { const float4 v = *reinterpret_cast<const float4*>(img + rb + x0 * CCH);
                       ax += w00 * v.x; ay += w00 * v.y; az += w00 * v.z; aw += w00 * v.w; }
            if (vx1) { const float4 v = *reinterpret_cast<const float4*>(img + rb + (x0 + 1) * CCH);
                       ax += w10 * v.x; ay += w10 * v.y; az += w10 * v.z; aw += w10 * v.w; }
        }
        if (vy1) {
            int rb = (y0 + 1) * HI * CCH;
            if (vx0) { const float4 v = *reinterpret_cast<const float4*>(img + rb + x0 * CCH);
                       ax += w01 * v.x; ay += w01 * v.y; az += w01 * v.z; aw += w01 * v.w; }
            if (vx1) { const float4 v = *reinterpret_cast<const float4*>(img + rb + (x0 + 1) * CCH);
                       ax += w11 * v.x; ay += w11 * v.y; az += w11 * v.z; aw += w11 * v.w; }
        }
    }
    ushort_t o[4] = { f2bf(ax), f2bf(ay), f2bf(az), f2bf(aw) };
    *reinterpret_cast<ushort4*>(coreb + (size_t)pix * CCH + g * CGC + c4) =
        *reinterpret_cast<ushort4*>(o);
}

extern "C" void kernel_launch(void* const* d_in, const int* in_sizes, int n_in,
                              void* d_out, int out_size, void* d_ws, size_t ws_size,
                              hipStream_t stream) {
    const float* x      = (const float*)d_in[0];
    const float* in_w   = (const float*)d_in[1];
    const float* in_b   = (const float*)d_in[2];
    const float* out_w  = (const float*)d_in[3];
    const float* out_b  = (const float*)d_in[4];
    const float* off_w  = (const float*)d_in[5];
    const float* off_b  = (const float*)d_in[6];
    const float* mask_w = (const float*)d_in[7];
    const float* mask_b = (const float*)d_in[8];
    const float* dw_k   = (const float*)d_in[9];
    const float* bn_g   = (const float*)d_in[10];
    const float* bn_b   = (const float*)d_in[11];
    const float* bn_m   = (const float*)d_in[12];
    const float* bn_v   = (const float*)d_in[13];

    float* ws = (float*)d_ws;
    float*    xpad  = ws;                                  // 4,460,544 f
    float*    offm  = xpad + 4460544;                      // 16384*256 f
    ushort_t* xb    = (ushort_t*)(offm + 4194304);         // 4,194,304 us
    ushort_t* x1b   = xb + 4194304;
    ushort_t* coreb = x1b + 4194304;
    ushort_t* WtIn  = coreb + 4194304;                     // 65,536 us
    ushort_t* WtOut = WtIn + 65536;
    ushort_t* W2t   = WtOut + 65536;
    float*    b2    = (float*)(W2t + 65536);               // 256 f
    float*    dwkT  = b2 + 256;                            // 9*256 f
    float*    bnS   = dwkT + 9 * 256;                      // 256 f
    float*    bnB   = bnS + 256;                           // 256 f

    // zero only the pad ring (interior fully overwritten by gemm_mfma<1>)
    zero_ring<<<NB * 260, 256, 0, stream>>>(xpad);

    pack_weights<<<256, 256, 0, stream>>>(in_w, out_w, off_w, mask_w, off_b, mask_b,
                                          dw_k, bn_g, bn_b, bn_m, bn_v,
                                          WtIn, WtOut, W2t, b2, dwkT, bnS, bnB);

    // 1) depthwise conv + BN + SiLU -> x1b, and cast x -> xb (fused, float4)
    dw_bn_silu<<<NPIX / 4, 256, 0, stream>>>(x, dwkT, bnS, bnB, x1b, xb);

    // 2) input projection -> padded image interior (fp32 out)
    gemm_mfma<1><<<dim3(NPIX / 64, 4), 256, 0, stream>>>(xb, WtIn, in_b, xpad);

    // 3) offset + mask projection (fused, N padded to 256)
    gemm_mfma<0><<<dim3(NPIX / 64, 4), 256, 0, stream>>>(x1b, W2t, b2, offm);

    // 4) deformable sampling (softmax in-register, wave-per-pixel, float4)
    dcn_sample<<<NPIX / 4, 256, 0, stream>>>(xpad, offm, coreb);

    // 5) output projection -> d_out
    gemm_mfma<0><<<dim3(NPIX / 64, 4), 256, 0, stream>>>(coreb, WtOut, out_b, (float*)d_out);
}

// Round 6
// 71.670 us; speedup vs baseline: 3.7984x; 1.1497x over previous
//
#include <hip/hip_runtime.h>
#include <math.h>

#define NB   4
#define HH   64
#define WW   64
#define CCH  256
#define GG   8
#define CGC  32
#define HI   66
#define NPIX 16384
#define OMWS 256   // offm row stride: 144 off + 72 mask + 40 pad

typedef unsigned short ushort_t;
typedef __attribute__((ext_vector_type(8))) short short8;
typedef __attribute__((ext_vector_type(4))) float floatx4;

__device__ inline ushort_t f2bf(float f) {
    union { float f; unsigned u; } v; v.f = f;
    unsigned r = v.u + 0x7FFF + ((v.u >> 16) & 1);   // round-to-nearest-even
    return (ushort_t)(r >> 16);
}
__device__ inline float bf2f(ushort_t u) {
    union { unsigned u; float f; } v; v.u = ((unsigned)u) << 16; return v.f;
}

__device__ inline void gload_lds16(const ushort_t* g, ushort_t* l) {
    __builtin_amdgcn_global_load_lds(
        (const __attribute__((address_space(1))) void*)g,
        (__attribute__((address_space(3))) void*)l, 16, 0, 0);
}

// ---------------- bf16 MFMA GEMM: C[M,256] = A[M,256] @ B[256,256] + bias ----
// A: bf16 [M][256] row-major. Bt: bf16 [n][k] (pre-transposed).
// MODE 0: fp32 out[row*256+col].  MODE 1: bf16 out = xpad [4,66,66,256] interior.
template<int MODE>
__global__ __launch_bounds__(256)
void gemm_mfma(const ushort_t* __restrict__ A, const ushort_t* __restrict__ Bt,
               const float* __restrict__ bias, void* __restrict__ outv)
{
    __shared__ ushort_t As[64 * 64];
    __shared__ ushort_t Bs[64 * 64];
    const int tid  = threadIdx.x;
    const int lane = tid & 63, wid = tid >> 6;
    const int wr = wid >> 1, wc = wid & 1;
    const int q = lane >> 4, r = lane & 15;
    const int row0 = blockIdx.x * 64, col0 = blockIdx.y * 64;

    const int srow = tid >> 3;                     // 0..31
    const int sg   = (tid & 7) ^ (srow & 7);       // XOR swizzle, granule units
    const ushort_t* ga = A  + (size_t)(row0 + srow) * 256 + sg * 8;
    const ushort_t* gb = Bt + (size_t)(col0 + srow) * 256 + sg * 8;
    ushort_t* la = As + tid * 8;
    ushort_t* lb = Bs + tid * 8;

    floatx4 acc[2][2] = {};

    for (int kb = 0; kb < 4; ++kb) {
        gload_lds16(ga + kb * 64,            la);
        gload_lds16(ga + kb * 64 + 32 * 256, la + 32 * 64);
        gload_lds16(gb + kb * 64,            lb);
        gload_lds16(gb + kb * 64 + 32 * 256, lb + 32 * 64);
        __syncthreads();
        #pragma unroll
        for (int kk = 0; kk < 2; ++kk) {
            short8 af[2], bf[2];
            const int gsw = ((kk * 4 + q) ^ (r & 7)) * 8;
            #pragma unroll
            for (int m = 0; m < 2; ++m) {
                af[m] = *(const short8*)&As[(wr * 32 + m * 16 + r) * 64 + gsw];
                bf[m] = *(const short8*)&Bs[(wc * 32 + m * 16 + r) * 64 + gsw];
            }
            #pragma unroll
            for (int m = 0; m < 2; ++m)
                #pragma unroll
                for (int n = 0; n < 2; ++n)
                    acc[m][n] = __builtin_amdgcn_mfma_f32_16x16x32_bf16(
                                    af[m], bf[n], acc[m][n], 0, 0, 0);
        }
        __syncthreads();
    }

    #pragma unroll
    for (int m = 0; m < 2; ++m) {
        #pragma unroll
        for (int n = 0; n < 2; ++n) {
            #pragma unroll
            for (int j = 0; j < 4; ++j) {
                int row = row0 + wr * 32 + m * 16 + q * 4 + j;
                int col = col0 + wc * 32 + n * 16 + r;
                float v = acc[m][n][j] + bias[col];
                if (MODE == 1) {
                    int nn = row >> 12, hh = (row >> 6) & 63, www = row & 63;
                    ((ushort_t*)outv)[(size_t)((nn * HI + hh + 1) * HI + (www + 1)) * CCH + col] = f2bf(v);
                } else {
                    ((float*)outv)[(size_t)row * 256 + col] = v;
                }
            }
        }
    }
}

// ---------------- zero only the pad ring of xpad (bf16) ----------------
__global__ __launch_bounds__(256)
void zero_ring(ushort_t* __restrict__ xpadb)
{
    int t = blockIdx.x;
    int n = t / 260, rp = t % 260;
    int h, w;
    if (rp < 66)       { h = 0;              w = rp; }
    else if (rp < 132) { h = 65;             w = rp - 66; }
    else if (rp < 196) { h = 1 + (rp - 132); w = 0; }
    else               { h = 1 + (rp - 196); w = 65; }
    xpadb[(size_t)((n * HI + h) * HI + w) * CCH + threadIdx.x] = 0;
}

// ---------------- pack weights ----------------
__global__ __launch_bounds__(256)
void pack_weights(const float* __restrict__ in_w, const float* __restrict__ out_w,
                  const float* __restrict__ off_w, const float* __restrict__ mask_w,
                  const float* __restrict__ off_b, const float* __restrict__ mask_b,
                  const float* __restrict__ dw_k, const float* __restrict__ bn_g,
                  const float* __restrict__ bn_b, const float* __restrict__ bn_m,
                  const float* __restrict__ bn_v,
                  ushort_t* __restrict__ WtIn, ushort_t* __restrict__ WtOut,
                  ushort_t* __restrict__ W2t, float* __restrict__ b2,
                  float* __restrict__ dwkT, float* __restrict__ bnS,
                  float* __restrict__ bnB)
{
    int n = blockIdx.x, k = threadIdx.x;
    WtIn [n * 256 + k] = f2bf(in_w [k * 256 + n]);
    WtOut[n * 256 + k] = f2bf(out_w[k * 256 + n]);
    float w2 = (n < 144) ? off_w[k * 144 + n]
             : (n < 216) ? mask_w[k * 72 + (n - 144)] : 0.f;
    W2t[n * 256 + k] = f2bf(w2);
    if (k == 0) b2[n] = (n < 144) ? off_b[n] : (n < 216) ? mask_b[n - 144] : 0.f;
    if (k < 9) dwkT[k * 256 + n] = dw_k[n * 9 + k];   // tap-major
    if (k == 9) {
        float s = bn_g[n] * rsqrtf(bn_v[n] + 1e-5f);
        bnS[n] = s;
        bnB[n] = bn_b[n] - bn_m[n] * s;
    }
}

// ---------------- depthwise 3x3 + BN + SiLU -> bf16 x1b, plus cast x -> xb ----
__global__ __launch_bounds__(256)
void dw_bn_silu(const float* __restrict__ x, const float* __restrict__ dwkT,
                const float* __restrict__ bnS, const float* __restrict__ bnB,
                ushort_t* __restrict__ x1b, ushort_t* __restrict__ xb)
{
    const int lane = threadIdx.x & 63, wid = threadIdx.x >> 6;
    const int pix = blockIdx.x * 4 + wid;
    const int n = pix >> 12, hw = pix & 4095, h = hw >> 6, w = hw & 63;
    const int c4 = lane << 2;

    const float4 cv = *reinterpret_cast<const float4*>(x + (size_t)pix * CCH + c4);
    ushort_t xo[4] = { f2bf(cv.x), f2bf(cv.y), f2bf(cv.z), f2bf(cv.w) };
    *reinterpret_cast<ushort4*>(xb + (size_t)pix * CCH + c4) = *reinterpret_cast<ushort4*>(xo);

    const float4 kc = *reinterpret_cast<const float4*>(dwkT + 4 * 256 + c4);
    float ax = cv.x * kc.x, ay = cv.y * kc.y, az = cv.z * kc.z, aw = cv.w * kc.w;

    #pragma unroll
    for (int tap = 0; tap < 9; ++tap) {
        if (tap == 4) continue;
        int hh = h + tap / 3 - 1, ww = w + tap % 3 - 1;
        if ((unsigned)hh < HH && (unsigned)ww < WW) {
            const float4 v = *reinterpret_cast<const float4*>(
                x + (size_t)((n * HH + hh) * WW + ww) * CCH + c4);
            const float4 kk = *reinterpret_cast<const float4*>(dwkT + tap * 256 + c4);
            ax += v.x * kk.x; ay += v.y * kk.y; az += v.z * kk.z; aw += v.w * kk.w;
        }
    }
    const float4 s = *reinterpret_cast<const float4*>(bnS + c4);
    const float4 b = *reinterpret_cast<const float4*>(bnB + c4);
    float yx = ax * s.x + b.x, yy = ay * s.y + b.y;
    float yz = az * s.z + b.z, yw = aw * s.w + b.w;
    yx = yx / (1.f + __expf(-yx));
    yy = yy / (1.f + __expf(-yy));
    yz = yz / (1.f + __expf(-yz));
    yw = yw / (1.f + __expf(-yw));
    ushort_t o[4] = { f2bf(yx), f2bf(yy), f2bf(yz), f2bf(yw) };
    *reinterpret_cast<ushort4*>(x1b + (size_t)pix * CCH + c4) = *reinterpret_cast<ushort4*>(o);
}

// ---------------- DCNv3 core: softmax + bilinear sampling on bf16 image -------
// 2 pixels per wave; lane (l=lane&31) owns group g=l>>2, 8 channels c8=(l&3)*8.
__global__ __launch_bounds__(256)
void dcn_sample(const ushort_t* __restrict__ xpadb, const float* __restrict__ om,
                ushort_t* __restrict__ coreb)
{
    const int tid = threadIdx.x;
    const int pix = blockIdx.x * 8 + (tid >> 5);
    const int l   = tid & 31;
    const int g = l >> 2, c8 = (l & 3) << 3;
    const int n = pix >> 12, hw = pix & 4095, h = hw >> 6, w = hw & 63;
    const float* __restrict__ omp = om + (size_t)pix * OMWS;

    float lg[9], mx = -1e30f;
    #pragma unroll
    for (int p = 0; p < 9; ++p) { lg[p] = omp[144 + g * 9 + p]; mx = fmaxf(mx, lg[p]); }
    float s = 0.f;
    #pragma unroll
    for (int p = 0; p < 9; ++p) { lg[p] = __expf(lg[p] - mx); s += lg[p]; }
    const float inv = 1.f / s;

    const ushort_t* __restrict__ img = xpadb + (size_t)n * HI * HI * CCH + g * CGC + c8;
    float acc[8] = {};
    #pragma unroll
    for (int p = 0; p < 9; ++p) {
        float ox = omp[g * 18 + p * 2 + 0];
        float oy = omp[g * 18 + p * 2 + 1];
        float xi = (float)(w + (p / 3)) + ox;
        float yi = (float)(h + (p % 3)) + oy;
        float x0f = floorf(xi), y0f = floorf(yi);
        int x0 = (int)x0f, y0 = (int)y0f;
        float fx = xi - x0f, fy = yi - y0f;
        float wgt = lg[p] * inv;
        float cw[4] = { (1.f - fx) * (1.f - fy) * wgt, fx * (1.f - fy) * wgt,
                        (1.f - fx) * fy * wgt,         fx * fy * wgt };
        #pragma unroll
        for (int cr = 0; cr < 4; ++cr) {
            int xc = x0 + (cr & 1), yc = y0 + (cr >> 1);
            if ((unsigned)xc < HI && (unsigned)yc < HI) {
                short8 raw = *reinterpret_cast<const short8*>(img + (size_t)(yc * HI + xc) * CCH);
                float wc = cw[cr];
                #pragma unroll
                for (int j = 0; j < 8; ++j) acc[j] += wc * bf2f((ushort_t)raw[j]);
            }
        }
    }
    ushort_t o[8];
    #pragma unroll
    for (int j = 0; j < 8; ++j) o[j] = f2bf(acc[j]);
    *reinterpret_cast<short8*>(coreb + (size_t)pix * CCH + g * CGC + c8) =
        *reinterpret_cast<short8*>(o);
}

extern "C" void kernel_launch(void* const* d_in, const int* in_sizes, int n_in,
                              void* d_out, int out_size, void* d_ws, size_t ws_size,
                              hipStream_t stream) {
    const float* x      = (const float*)d_in[0];
    const float* in_w   = (const float*)d_in[1];
    const float* in_b   = (const float*)d_in[2];
    const float* out_w  = (const float*)d_in[3];
    const float* out_b  = (const float*)d_in[4];
    const float* off_w  = (const float*)d_in[5];
    const float* off_b  = (const float*)d_in[6];
    const float* mask_w = (const float*)d_in[7];
    const float* mask_b = (const float*)d_in[8];
    const float* dw_k   = (const float*)d_in[9];
    const float* bn_g   = (const float*)d_in[10];
    const float* bn_b   = (const float*)d_in[11];
    const float* bn_m   = (const float*)d_in[12];
    const float* bn_v   = (const float*)d_in[13];

    float* ws = (float*)d_ws;
    float*    offm  = ws;                                  // 16384*256 f
    ushort_t* xpadb = (ushort_t*)(offm + 4194304);         // 4,460,544 us
    ushort_t* xb    = xpadb + 4460544;                     // 4,194,304 us
    ushort_t* x1b   = xb + 4194304;
    ushort_t* coreb = x1b + 4194304;
    ushort_t* WtIn  = coreb + 4194304;                     // 65,536 us
    ushort_t* WtOut = WtIn + 65536;
    ushort_t* W2t   = WtOut + 65536;
    float*    b2    = (float*)(W2t + 65536);               // 256 f
    float*    dwkT  = b2 + 256;                            // 9*256 f
    float*    bnS   = dwkT + 9 * 256;                      // 256 f
    float*    bnB   = bnS + 256;                           // 256 f

    // zero only the pad ring (interior fully overwritten by gemm_mfma<1>)
    zero_ring<<<NB * 260, 256, 0, stream>>>(xpadb);

    pack_weights<<<256, 256, 0, stream>>>(in_w, out_w, off_w, mask_w, off_b, mask_b,
                                          dw_k, bn_g, bn_b, bn_m, bn_v,
                                          WtIn, WtOut, W2t, b2, dwkT, bnS, bnB);

    // 1) depthwise conv + BN + SiLU -> x1b, and cast x -> xb (fused, float4)
    dw_bn_silu<<<NPIX / 4, 256, 0, stream>>>(x, dwkT, bnS, bnB, x1b, xb);

    // 2) input projection -> padded image interior (bf16 out)
    gemm_mfma<1><<<dim3(NPIX / 64, 4), 256, 0, stream>>>(xb, WtIn, in_b, xpadb);

    // 3) offset + mask projection (fused, N padded to 256)
    gemm_mfma<0><<<dim3(NPIX / 64, 4), 256, 0, stream>>>(x1b, W2t, b2, offm);

    // 4) deformable sampling on bf16 image (2 px/wave, 16B gathers)
    dcn_sample<<<NPIX / 8, 256, 0, stream>>>(xpadb, offm, coreb);

    // 5) output projection -> d_out
    gemm_mfma<0><<<dim3(NPIX / 64, 4), 256, 0, stream>>>(coreb, WtOut, out_b, (float*)d_out);
}